// Round 13
// baseline (169.511 us; speedup 1.0000x reference)
//
#include <hip/hip_runtime.h>

#define C_DIM 128
#define HW_DIM 6144

typedef __attribute__((ext_vector_type(8))) short short8;
typedef __attribute__((ext_vector_type(4))) float f32x4;

static __device__ __forceinline__ unsigned short f2bf(float x) {
    unsigned int u = __builtin_bit_cast(unsigned int, x);
    u = (u + 0x7FFFu + ((u >> 16) & 1u)) >> 16;
    return (unsigned short)u;
}
static __device__ __forceinline__ float bf2f(unsigned short u) {
    unsigned int x = ((unsigned int)u) << 16;
    return __builtin_bit_cast(float, x);
}
static __device__ __forceinline__ unsigned int pack2(float a, float b) {
    return (unsigned int)f2bf(a) | ((unsigned int)f2bf(b) << 16);
}
static __device__ __forceinline__ f32x4 mfma_bf16(short8 a, short8 b, f32x4 c) {
    return __builtin_amdgcn_mfma_f32_16x16x32_bf16(a, b, c, 0, 0, 0);
}
// async global->LDS, 16B per lane; LDS dest linear, global source pre-swizzled.
static __device__ __forceinline__ void gload16(const unsigned short* g,
                                               unsigned short* l) {
    __builtin_amdgcn_global_load_lds(
        (const __attribute__((address_space(1))) unsigned int*)g,
        (__attribute__((address_space(3))) unsigned int*)l, 16, 0, 0);
}
// MFMA A-fragment (bf16) directly from global fp32 W[o][c].
static __device__ __forceinline__ short8 wfrag(const float* Wrow) {
    float4 a = *(const float4*)Wrow;
    float4 b = *(const float4*)(Wrow + 4);
    unsigned int u[4] = {pack2(a.x, a.y), pack2(a.z, a.w),
                         pack2(b.x, b.y), pack2(b.z, b.w)};
    return *(const short8*)u;
}

// ---------------------------------------------------------------------------
// r27 launch A: QKV projections, BALANCED 3-way z-split.
//   z=0: query -> conv1 -> conv2 -> Qbf (scaled)   (~64 MFMA + 1 epilogue)
//   z=1: key   -> conv1 -> conv2 -> Kbf            (~64 MFMA + 1 epilogue)
//   z=2: key   -> v-conv -> Vbf                    (~32 MFMA + 1 epilogue)
// r23's key-dedup chained k+v into one z (96-MFMA serial critical path,
// 1.5x the balanced value) to save 12.6 MB HBM — bad trade: the save is
// parallel BW (~2 µs), the cost was serial time. Reverted to 576 blocks
// with T14 staging kept on all paths.
// ---------------------------------------------------------------------------
struct ProjArgs {
    const float* query; const float* key;
    const float* q_w1; const float* q_g1; const float* q_b1;
    const float* q_w2; const float* q_g2; const float* q_b2;
    const float* k_w1; const float* k_g1; const float* k_b1;
    const float* k_w2; const float* k_g2; const float* k_b2;
    const float* v_w;  const float* v_g;  const float* v_b;
    unsigned short* Qbf; unsigned short* Kbf; unsigned short* Vbf;
    float qscale;
};

__global__ __launch_bounds__(256)
void qkv_proj(ProjArgs A)
{
    __shared__ __align__(16) unsigned short Xt[64 * 128];   // 16 KB X tile
    __shared__ __align__(16) unsigned short Ct[64 * 128];   // 16 KB mid/epi

    const int t    = threadIdx.x;
    const int b    = blockIdx.y;
    const int p0   = blockIdx.x * 64;
    const int z    = blockIdx.z;            // 0:q-chain 1:k-chain 2:v-conv
    const int wave = t >> 6;
    const int lane = t & 63;
    const int quad = lane >> 4;
    const int l16  = lane & 15;
    const float BNRS = 0.99999500003749972f;  // 1/sqrt(1 + 1e-5)

    const float* Xg = (z == 0) ? A.query : A.key;

    // ---- T14 step 1: issue ALL X loads (HBM) into registers ----
    const float* Xb = Xg + (size_t)b * C_DIM * HW_DIM;
    float4 xa[4], xb4[4];
#pragma unroll
    for (int i = 0; i < 4; ++i) {
        int w = i * 256 + t;              // 1024 work items
        int c = (w >> 4) * 2;             // even row
        int p = (w & 15) * 4;             // 4-col group
        xa[i]  = *(const float4*)&Xb[(size_t)c * HW_DIM + p0 + p];
        xb4[i] = *(const float4*)&Xb[(size_t)(c + 1) * HW_DIM + p0 + p];
    }

    // ---- T14 step 2: W fragments (L2) — latency fills the HBM window ----
    short8 af1[2][4], af2[2][4];
    if (z == 2) {
#pragma unroll
        for (int mi = 0; mi < 2; ++mi) {
            int o = (wave * 2 + mi) * 16 + l16;
#pragma unroll
            for (int s = 0; s < 4; ++s)
                af1[mi][s] = wfrag(A.v_w + o * C_DIM + s * 32 + quad * 8);
        }
    } else {
        const float* W1 = (z == 0) ? A.q_w1 : A.k_w1;
        const float* W2 = (z == 0) ? A.q_w2 : A.k_w2;
#pragma unroll
        for (int mi = 0; mi < 2; ++mi) {
            int o = (wave * 2 + mi) * 16 + l16;
#pragma unroll
            for (int s = 0; s < 4; ++s) {
                af1[mi][s] = wfrag(W1 + o * C_DIM + s * 32 + quad * 8);
                af2[mi][s] = wfrag(W2 + o * C_DIM + s * 32 + quad * 8);
            }
        }
    }

    // ---- T14 step 3: convert + LDS write ----
#pragma unroll
    for (int i = 0; i < 4; ++i) {
        int w = i * 256 + t;
        int c = (w >> 4) * 2;
        int p = (w & 15) * 4;
        float av[4] = {xa[i].x, xa[i].y, xa[i].z, xa[i].w};
        float bv[4] = {xb4[i].x, xb4[i].y, xb4[i].z, xb4[i].w};
#pragma unroll
        for (int j = 0; j < 4; ++j) {
            int pp = p + j;
            int addr = pp * 128 + (((c >> 3) ^ (pp & 15)) * 8) + (c & 7);
            *(unsigned int*)&Xt[addr] = pack2(av[j], bv[j]);
        }
    }
    __syncthreads();

    // ---- conv1 (or v-conv) GEMM from Xt ----
    f32x4 acc[2][4];
#pragma unroll
    for (int mi = 0; mi < 2; ++mi)
#pragma unroll
        for (int nt = 0; nt < 4; ++nt) acc[mi][nt] = (f32x4){0.f, 0.f, 0.f, 0.f};
#pragma unroll
    for (int nt = 0; nt < 4; ++nt)
#pragma unroll
        for (int s = 0; s < 4; ++s) {
            short8 bf = *(const short8*)
                &Xt[(nt * 16 + l16) * 128 + (((4 * s + quad) ^ l16) * 8)];
            acc[0][nt] = mfma_bf16(af1[0][s], bf, acc[0][nt]);
            acc[1][nt] = mfma_bf16(af1[1][s], bf, acc[1][nt]);
        }

    if (z == 2) {
        // ---- v path: BN + LReLU, epilogue bf16 [b][c][pos] via Ct ----
#pragma unroll
        for (int mi = 0; mi < 2; ++mi)
#pragma unroll
            for (int r = 0; r < 4; ++r) {
                int o = (wave * 2 + mi) * 16 + quad * 4 + r;
                float sc = A.v_g[o] * BNRS, bb = A.v_b[o];
#pragma unroll
                for (int nt = 0; nt < 4; ++nt) {
                    float y = fmaf(acc[mi][nt][r], sc, bb);
                    acc[mi][nt][r] = y > 0.f ? y : 0.1f * y;
                }
            }
#pragma unroll
        for (int mi = 0; mi < 2; ++mi)
#pragma unroll
            for (int nt = 0; nt < 4; ++nt)
#pragma unroll
                for (int r = 0; r < 4; ++r) {
                    int o = (wave * 2 + mi) * 16 + quad * 4 + r;
                    int p = nt * 16 + l16;
                    Ct[o * 64 + (((p >> 3) ^ (o & 7)) * 8) + (p & 7)] =
                        f2bf(acc[mi][nt][r]);
                }
        __syncthreads();
#pragma unroll
        for (int i = 0; i < 4; ++i) {          // all 1024 chunks (r14 fix)
            int idx = t + 256 * i;
            int o = idx >> 3, ch = idx & 7;
            uint4 v = *(const uint4*)&Ct[o * 64 + ((ch ^ (o & 7)) * 8)];
            *(uint4*)&A.Vbf[((size_t)b * C_DIM + o) * HW_DIM + p0 + ch * 8] = v;
        }
        return;
    }

    // ---- q/k chain: BN1 + LReLU ----
    const float* G1 = (z == 0) ? A.q_g1 : A.k_g1;
    const float* B1 = (z == 0) ? A.q_b1 : A.k_b1;
    const float* G2 = (z == 0) ? A.q_g2 : A.k_g2;
    const float* B2 = (z == 0) ? A.q_b2 : A.k_b2;
#pragma unroll
    for (int mi = 0; mi < 2; ++mi)
#pragma unroll
        for (int r = 0; r < 4; ++r) {
            int o = (wave * 2 + mi) * 16 + quad * 4 + r;
            float sc = G1[o] * BNRS, bb = B1[o];
#pragma unroll
            for (int nt = 0; nt < 4; ++nt) {
                float y = fmaf(acc[mi][nt][r], sc, bb);
                acc[mi][nt][r] = y > 0.f ? y : 0.1f * y;
            }
        }

    // ---- mid -> Ct (B-operand swizzle) ----
#pragma unroll
    for (int mi = 0; mi < 2; ++mi)
#pragma unroll
        for (int nt = 0; nt < 4; ++nt)
#pragma unroll
            for (int r = 0; r < 4; ++r) {
                int o = (wave * 2 + mi) * 16 + quad * 4 + r;
                int p = nt * 16 + l16;
                Ct[p * 128 + (((o >> 3) ^ (p & 15)) * 8) + (o & 7)] =
                    f2bf(acc[mi][nt][r]);
            }
    __syncthreads();

    // ---- conv2 GEMM from Ct ----
#pragma unroll
    for (int mi = 0; mi < 2; ++mi)
#pragma unroll
        for (int nt = 0; nt < 4; ++nt) acc[mi][nt] = (f32x4){0.f, 0.f, 0.f, 0.f};
#pragma unroll
    for (int nt = 0; nt < 4; ++nt)
#pragma unroll
        for (int s = 0; s < 4; ++s) {
            short8 bf = *(const short8*)
                &Ct[(nt * 16 + l16) * 128 + (((4 * s + quad) ^ l16) * 8)];
            acc[0][nt] = mfma_bf16(af2[0][s], bf, acc[0][nt]);
            acc[1][nt] = mfma_bf16(af2[1][s], bf, acc[1][nt]);
        }
    // BN2 + LReLU
#pragma unroll
    for (int mi = 0; mi < 2; ++mi)
#pragma unroll
        for (int r = 0; r < 4; ++r) {
            int o = (wave * 2 + mi) * 16 + quad * 4 + r;
            float sc = G2[o] * BNRS, bb = B2[o];
#pragma unroll
            for (int nt = 0; nt < 4; ++nt) {
                float y = fmaf(acc[mi][nt][r], sc, bb);
                acc[mi][nt][r] = y > 0.f ? y : 0.1f * y;
            }
        }

    // ---- epilogue: bf16 [b][pos][c] via Xt (dead after conv1 + mid-sync) ----
    unsigned short* O = (z == 0) ? A.Qbf : A.Kbf;
    float os = (z == 0) ? A.qscale : 1.0f;
#pragma unroll
    for (int mi = 0; mi < 2; ++mi)
#pragma unroll
        for (int nt = 0; nt < 4; ++nt)
#pragma unroll
            for (int r = 0; r < 4; ++r) {
                int o = (wave * 2 + mi) * 16 + quad * 4 + r;
                int p = nt * 16 + l16;
                Xt[p * 128 + (((o >> 3) ^ (p & 15)) * 8) + (o & 7)] =
                    f2bf(acc[mi][nt][r] * os);
            }
    __syncthreads();
#pragma unroll
    for (int i = 0; i < 4; ++i) {
        int idx = t + 256 * i;
        int p = idx >> 4, ch = idx & 15;
        uint4 v = *(const uint4*)&Xt[p * 128 + ((ch ^ (p & 15)) * 8)];
        *(uint4*)&O[((size_t)b * HW_DIM + p0 + p) * C_DIM + ch * 8] = v;
    }
}

// ---------------------------------------------------------------------------
// Flash attention (r26 EXACT — 55.2 µs, 0 bank conflicts; untouched).
// ---------------------------------------------------------------------------
template <int NSPLIT>
__global__ __launch_bounds__(256, 2)
void flash_attn(const unsigned short* __restrict__ Q,
                const unsigned short* __restrict__ K,
                const unsigned short* __restrict__ V,
                unsigned short* __restrict__ Pint,
                float* __restrict__ Lint)
{
    __shared__ __align__(16) unsigned short TM[2][16384];     // 64 KB dbuf
    __shared__ __align__(16) unsigned short Plds[4][16][64];  // 8 KB swizzled

    const int t    = threadIdx.x;
    const int wave = t >> 6;
    const int lane = t & 63;
    const int quad = lane >> 4;
    const int l16  = lane & 15;

    constexpr int KS_BITS = (NSPLIT == 8) ? 3 : 2;
    const int bid  = blockIdx.x;
    const int ks   = bid & (NSPLIT - 1);        // = XCD under round-robin
    const int fb   = (bid >> KS_BITS) & 1;
    const int qblk = bid >> (KS_BITS + 1);      // 0..31
    const int q0   = qblk * 192 + wave * 48;
    const int kbeg = ks * (HW_DIM / NSPLIT);

    const unsigned short* Qb = Q + (size_t)fb * HW_DIM * C_DIM;
    const unsigned short* Kb = K + (size_t)fb * HW_DIM * C_DIM;
    const unsigned short* Vb = V + (size_t)fb * C_DIM * HW_DIM;

    short8 qf[3][4];
#pragma unroll
    for (int rt = 0; rt < 3; ++rt)
#pragma unroll
        for (int s = 0; s < 4; ++s)
            qf[rt][s] = *(const short8*)
                &Qb[(size_t)(q0 + rt * 16 + l16) * C_DIM + s * 32 + quad * 8];

    f32x4 O[3][8];
#pragma unroll
    for (int rt = 0; rt < 3; ++rt)
#pragma unroll
        for (int h = 0; h < 8; ++h) O[rt][h] = (f32x4){0.f, 0.f, 0.f, 0.f};
    float lsum[3][4] = {{0,0,0,0},{0,0,0,0},{0,0,0,0}};

    int koff[4], voff[4];
#pragma unroll
    for (int j = 0; j < 4; ++j) {
        int ci = t + 256 * j;
        int kr = ci >> 4, kc = ci & 15;
        koff[j] = kr * C_DIM + ((kc ^ (kr & 15)) << 3);
        int vr = ci >> 3, vc = ci & 7;
        voff[j] = vr * HW_DIM + ((vc ^ (vr & 7)) << 3);
    }

    const int NIT = (HW_DIM / NSPLIT) / 64;

    // prologue: stage tile 0 into buf 0
    {
        const unsigned short* Ksrc = Kb + (size_t)kbeg * C_DIM;
        const unsigned short* Vsrc = Vb + kbeg;
        unsigned short* Kt = TM[0];
        unsigned short* Vt = TM[0] + 8192;
#pragma unroll
        for (int j = 0; j < 4; ++j) {
            int ci = t + 256 * j;
            gload16(Ksrc + koff[j], &Kt[ci * 8]);
            gload16(Vsrc + voff[j], &Vt[ci * 8]);
        }
    }
    __syncthreads();

    int cur = 0;
    for (int it = 0; it < NIT; ++it) {
        // ---- prefetch K(it+1) FIRST (lands during compute) ----
        const int kb2 = kbeg + (it + 1) * 64;
        if (it + 1 < NIT) {
            const unsigned short* Ksrc = Kb + (size_t)kb2 * C_DIM;
            unsigned short* Kt2 = TM[cur ^ 1];
#pragma unroll
            for (int j = 0; j < 4; ++j) {
                int ci = t + 256 * j;
                gload16(Ksrc + koff[j], &Kt2[ci * 8]);
            }
        }

        unsigned short* Kt = TM[cur];
        unsigned short* Vt = TM[cur] + 8192;

        // ---- QK^T (setprio-wrapped MFMA cluster) ----
        f32x4 S[3][4];
#pragma unroll
        for (int rt = 0; rt < 3; ++rt)
#pragma unroll
            for (int n = 0; n < 4; ++n) S[rt][n] = (f32x4){0.f, 0.f, 0.f, 0.f};
        __builtin_amdgcn_s_setprio(1);
#pragma unroll
        for (int n = 0; n < 4; ++n)
#pragma unroll
            for (int s = 0; s < 4; ++s) {
                short8 kf = *(const short8*)
                    &Kt[(size_t)(n * 16 + l16) * 128 + (((4 * s + quad) ^ l16) * 8)];
                S[0][n] = mfma_bf16(qf[0][s], kf, S[0][n]);
                S[1][n] = mfma_bf16(qf[1][s], kf, S[1][n]);
                S[2][n] = mfma_bf16(qf[2][s], kf, S[2][n]);
            }
        __builtin_amdgcn_s_setprio(0);

        // ---- prefetch V(it+1) (staggered after QK^T) ----
        if (it + 1 < NIT) {
            const unsigned short* Vsrc = Vb + kb2;
            unsigned short* Vt2 = TM[cur ^ 1] + 8192;
#pragma unroll
            for (int j = 0; j < 4; ++j) {
                int ci = t + 256 * j;
                gload16(Vsrc + voff[j], &Vt2[ci * 8]);
            }
        }

        // ---- exp2 -> Plds (wave-private, swizzled) -> pa fragments ----
        short8 pa[3][2];
#pragma unroll
        for (int rt = 0; rt < 3; ++rt) {
#pragma unroll
            for (int n = 0; n < 4; ++n)
#pragma unroll
                for (int r = 0; r < 4; ++r) {
                    float e = __builtin_amdgcn_exp2f(S[rt][n][r]);
                    lsum[rt][r] += e;
                    int row = quad * 4 + r;
                    Plds[wave][row][(((n * 2 + (l16 >> 3)) ^ (row & 7)) << 3) | (l16 & 7)] =
                        f2bf(e);
                }
            pa[rt][0] = *(const short8*)&Plds[wave][l16][((quad       ^ (l16 & 7)) << 3)];
            pa[rt][1] = *(const short8*)&Plds[wave][l16][(((4 + quad) ^ (l16 & 7)) << 3)];
        }

        // ---- PV (setprio-wrapped MFMA cluster) ----
        const int m = l16 & 7;
        __builtin_amdgcn_s_setprio(1);
#pragma unroll
        for (int h = 0; h < 8; ++h) {
            short8 v0 = *(const short8*)&Vt[(size_t)(h * 16 + l16) * 64 + ((quad ^ m) * 8)];
            short8 v1 = *(const short8*)&Vt[(size_t)(h * 16 + l16) * 64 + (((quad + 4) ^ m) * 8)];
            O[0][h] = mfma_bf16(pa[0][0], v0, O[0][h]);
            O[0][h] = mfma_bf16(pa[0][1], v1, O[0][h]);
            O[1][h] = mfma_bf16(pa[1][0], v0, O[1][h]);
            O[1][h] = mfma_bf16(pa[1][1], v1, O[1][h]);
            O[2][h] = mfma_bf16(pa[2][0], v0, O[2][h]);
            O[2][h] = mfma_bf16(pa[2][1], v1, O[2][h]);
        }
        __builtin_amdgcn_s_setprio(0);

        // ONE barrier: drains prefetch (overlapped with compute above) and
        // guards buf reuse for the next iteration.
        __syncthreads();
        cur ^= 1;
    }

#pragma unroll
    for (int off = 1; off < 16; off <<= 1)
#pragma unroll
        for (int rt = 0; rt < 3; ++rt)
#pragma unroll
            for (int r = 0; r < 4; ++r)
                lsum[rt][r] += __shfl_xor(lsum[rt][r], off, 64);

    // ---- write P/L partials (interleaved layout) ----
#pragma unroll
    for (int rt = 0; rt < 3; ++rt)
#pragma unroll
        for (int r = 0; r < 4; ++r) {
            int lrow = wave * 48 + rt * 16 + quad * 4 + r;
            size_t row = (size_t)fb * HW_DIM + qblk * 192 + lrow;
            if (l16 == 0) Lint[row * NSPLIT + ks] = lsum[rt][r];
#pragma unroll
            for (int h = 0; h < 8; ++h)
                Pint[row * (NSPLIT * C_DIM) + ks * C_DIM + h * 16 + l16] =
                    f2bf(O[rt][h][r]);
        }
}

// ---------------------------------------------------------------------------
// Launch C: combine + out-conv + residual (r24 EXACT — T14 batching).
// ---------------------------------------------------------------------------
template <int NPARTS>
__global__ __launch_bounds__(256)
void combine_out(const unsigned short* __restrict__ Pint,
                 const float* __restrict__ Lint,
                 const float* __restrict__ OW,
                 const float* __restrict__ OG,
                 const float* __restrict__ OB,
                 const float* __restrict__ RESID,
                 float* __restrict__ OUT)
{
    __shared__ __align__(16) unsigned short Xt[32 * 128];   // 8 KB
    __shared__ float invl[32];

    const int t    = threadIdx.x;
    const int b    = blockIdx.y;
    const int p0   = blockIdx.x * 32;
    const int wave = t >> 6;
    const int lane = t & 63;
    const int quad = lane >> 4;
    const int l16  = lane & 15;
    const float BNRS = 0.99999500003749972f;

    // ---- T14: issue ALL partial loads first ----
    uint4 pv[2][NPARTS];
#pragma unroll
    for (int i = 0; i < 2; ++i) {
        int idx = t + 256 * i;
        int p = idx >> 4, ch = idx & 15;
        size_t row = (size_t)b * HW_DIM + p0 + p;
        size_t base = row * (NPARTS * C_DIM) + ch * 8;
#pragma unroll
        for (int pr = 0; pr < NPARTS; ++pr)
            pv[i][pr] = *(const uint4*)&Pint[base + (size_t)pr * C_DIM];
    }

    // ---- W fragments (L2) while partials stream ----
    short8 af[2][4];
#pragma unroll
    for (int mi = 0; mi < 2; ++mi) {
        int o = (wave * 2 + mi) * 16 + l16;
#pragma unroll
        for (int s = 0; s < 4; ++s)
            af[mi][s] = wfrag(OW + o * C_DIM + s * 32 + quad * 8);
    }

    if (t < 32) {
        size_t row = (size_t)b * HW_DIM + p0 + t;
        float s = 0.f;
#pragma unroll
        for (int pr = 0; pr < NPARTS; ++pr)
            s += Lint[row * NPARTS + pr];
        invl[t] = 1.0f / s;
    }
    __syncthreads();

    // ---- accumulate + normalize -> Xt ----
#pragma unroll
    for (int i = 0; i < 2; ++i) {
        int idx = t + 256 * i;
        int p = idx >> 4, ch = idx & 15;
        float acc8[8] = {0.f, 0.f, 0.f, 0.f, 0.f, 0.f, 0.f, 0.f};
#pragma unroll
        for (int pr = 0; pr < NPARTS; ++pr) {
            const unsigned int* ap = (const unsigned int*)&pv[i][pr];
#pragma unroll
            for (int j = 0; j < 4; ++j) {
                acc8[2 * j]     += bf2f((unsigned short)(ap[j] & 0xFFFF));
                acc8[2 * j + 1] += bf2f((unsigned short)(ap[j] >> 16));
            }
        }
        float s = invl[p];
        unsigned int w[4];
#pragma unroll
        for (int j = 0; j < 4; ++j)
            w[j] = pack2(acc8[2 * j] * s, acc8[2 * j + 1] * s);
        *(uint4*)&Xt[p * 128 + ((ch ^ (p & 15)) * 8)] = *(uint4*)w;
    }
    __syncthreads();

    f32x4 acc[2][2];
#pragma unroll
    for (int mi = 0; mi < 2; ++mi)
#pragma unroll
        for (int nt = 0; nt < 2; ++nt) acc[mi][nt] = (f32x4){0.f, 0.f, 0.f, 0.f};
#pragma unroll
    for (int nt = 0; nt < 2; ++nt)
#pragma unroll
        for (int s = 0; s < 4; ++s) {
            short8 bf = *(const short8*)
                &Xt[(nt * 16 + l16) * 128 + (((4 * s + quad) ^ l16) * 8)];
            acc[0][nt] = mfma_bf16(af[0][s], bf, acc[0][nt]);
            acc[1][nt] = mfma_bf16(af[1][s], bf, acc[1][nt]);
        }

#pragma unroll
    for (int mi = 0; mi < 2; ++mi)
#pragma unroll
        for (int r = 0; r < 4; ++r) {
            int o = (wave * 2 + mi) * 16 + quad * 4 + r;
            float sc = OG[o] * BNRS, bb = OB[o];
#pragma unroll
            for (int nt = 0; nt < 2; ++nt) {
                float y = fmaf(acc[mi][nt][r], sc, bb);
                y = y > 0.f ? y : 0.1f * y;
                size_t g = ((size_t)b * C_DIM + o) * HW_DIM + p0 + nt * 16 + l16;
                OUT[g] = y + RESID[g];
            }
        }
}

// ---------------------------------------------------------------------------
extern "C" void kernel_launch(void* const* d_in, const int* in_sizes, int n_in,
                              void* d_out, int out_size, void* d_ws, size_t ws_size,
                              hipStream_t stream)
{
    // Workspace: [ Pint: nsplit*3145728 B ][ Qbf ][ Kbf ][ Vbf ][ Lint: nsplit*49152 B ]
    const size_t PPART = (size_t)2 * HW_DIM * C_DIM * 2;  // 3,145,728 B
    const size_t LPART = (size_t)2 * HW_DIM * 4;          // 49,152 B
    const int nsplit = (ws_size >= 11 * PPART + 8 * LPART) ? 8 : 4;

    char* ws = (char*)d_ws;
    unsigned short* Pint = (unsigned short*)ws;
    unsigned short* Qbf = (unsigned short*)(ws + (size_t)nsplit * PPART);
    unsigned short* Kbf = (unsigned short*)(ws + (size_t)nsplit * PPART + PPART);
    unsigned short* Vbf = (unsigned short*)(ws + (size_t)nsplit * PPART + 2 * PPART);
    float*          Lint = (float*)(ws + (size_t)nsplit * PPART + 3 * PPART);
    float* outp = (float*)d_out;

    // Launch A: balanced 3-way QKV projections. Grid (96,2,3)=576 blocks.
    {
        ProjArgs pa;
        pa.query = (const float*)d_in[0];
        pa.key   = (const float*)d_in[1];
        pa.q_w1 = (const float*)d_in[2];  pa.q_g1 = (const float*)d_in[3];
        pa.q_b1 = (const float*)d_in[4];
        pa.q_w2 = (const float*)d_in[5];  pa.q_g2 = (const float*)d_in[6];
        pa.q_b2 = (const float*)d_in[7];
        pa.k_w1 = (const float*)d_in[8];  pa.k_g1 = (const float*)d_in[9];
        pa.k_b1 = (const float*)d_in[10];
        pa.k_w2 = (const float*)d_in[11]; pa.k_g2 = (const float*)d_in[12];
        pa.k_b2 = (const float*)d_in[13];
        pa.v_w  = (const float*)d_in[14]; pa.v_g  = (const float*)d_in[15];
        pa.v_b  = (const float*)d_in[16];
        pa.Qbf = Qbf; pa.Kbf = Kbf; pa.Vbf = Vbf;
        pa.qscale = 0.08838834764831845f * 1.44269504088896340f;
        hipLaunchKernelGGL(qkv_proj, dim3(HW_DIM / 64, 2, 3), dim3(256),
                           0, stream, pa);
    }

    // Flash: r26 structure (unchanged). 512 blocks, rt=3.
    if (nsplit == 8) {
        hipLaunchKernelGGL(HIP_KERNEL_NAME(flash_attn<8>),
                           dim3(2 * (HW_DIM / 192) * 8), dim3(256),
                           0, stream, Qbf, Kbf, Vbf, Pint, Lint);
    } else {
        hipLaunchKernelGGL(HIP_KERNEL_NAME(flash_attn<4>),
                           dim3(2 * (HW_DIM / 192) * 4), dim3(256),
                           0, stream, Qbf, Kbf, Vbf, Pint, Lint);
    }

    // Launch C: combine (batched streaming reads) + out-conv + residual.
    {
        const float* o_w = (const float*)d_in[17];
        const float* o_g = (const float*)d_in[18];
        const float* o_b = (const float*)d_in[19];
        if (nsplit == 8) {
            hipLaunchKernelGGL(HIP_KERNEL_NAME(combine_out<8>),
                               dim3(HW_DIM / 32, 2), dim3(256), 0, stream,
                               Pint, Lint, o_w, o_g, o_b,
                               (const float*)d_in[0], outp);
        } else {
            hipLaunchKernelGGL(HIP_KERNEL_NAME(combine_out<4>),
                               dim3(HW_DIM / 32, 2), dim3(256), 0, stream,
                               Pint, Lint, o_w, o_g, o_b,
                               (const float*)d_in[0], outp);
        }
    }
}

// Round 14
// 167.708 us; speedup vs baseline: 1.0108x; 1.0108x over previous
//
#include <hip/hip_runtime.h>

#define C_DIM 128
#define HW_DIM 6144

typedef __attribute__((ext_vector_type(8))) short short8;
typedef __attribute__((ext_vector_type(4))) float f32x4;

static __device__ __forceinline__ unsigned short f2bf(float x) {
    unsigned int u = __builtin_bit_cast(unsigned int, x);
    u = (u + 0x7FFFu + ((u >> 16) & 1u)) >> 16;
    return (unsigned short)u;
}
static __device__ __forceinline__ float bf2f(unsigned short u) {
    unsigned int x = ((unsigned int)u) << 16;
    return __builtin_bit_cast(float, x);
}
static __device__ __forceinline__ unsigned int pack2(float a, float b) {
    return (unsigned int)f2bf(a) | ((unsigned int)f2bf(b) << 16);
}
static __device__ __forceinline__ f32x4 mfma_bf16(short8 a, short8 b, f32x4 c) {
    return __builtin_amdgcn_mfma_f32_16x16x32_bf16(a, b, c, 0, 0, 0);
}
// async global->LDS, 16B per lane; LDS dest linear, global source pre-swizzled.
static __device__ __forceinline__ void gload16(const unsigned short* g,
                                               unsigned short* l) {
    __builtin_amdgcn_global_load_lds(
        (const __attribute__((address_space(1))) unsigned int*)g,
        (__attribute__((address_space(3))) unsigned int*)l, 16, 0, 0);
}
// MFMA A-fragment (bf16) directly from global fp32 W[o][c].
static __device__ __forceinline__ short8 wfrag(const float* Wrow) {
    float4 a = *(const float4*)Wrow;
    float4 b = *(const float4*)(Wrow + 4);
    unsigned int u[4] = {pack2(a.x, a.y), pack2(a.z, a.w),
                         pack2(b.x, b.y), pack2(b.z, b.w)};
    return *(const short8*)u;
}

// ---------------------------------------------------------------------------
// r28 == r24 EXACT (best-measured: 168.3 µs total). Session close-out:
// r25 (occupancy via KVBLK=32: bank-conflict regression), r26 (setprio +
// staggered prefetch: null), r27 (balanced A split: null) all landed within
// the harness's ±3-10% run-to-run noise band; per methodology, sub-noise
// deltas don't earn a commit. This reverts to the best-proven configuration:
//   A: key staged once + T14 async-stage split (384 blocks)
//   flash: KVBLK=64, rt=3, double-buffered single-barrier pipeline,
//          interleaved P/L partial layout (512 blocks, 2/CU, 0 conflicts)
//   C: interleaved-partial streaming combine + T14 load batching (384 blocks)
// Remaining structural constraints (documented, not reachable safely here):
//   - flash ~55µs is latency-structure bound (MfmaUtil ~27%); next lever is
//     the counted-vmcnt inline-asm pipeline (T3/T4), high regression risk.
//   - ~60µs fixed per-replay overhead; whole-graph fusion attempts all
//     failed (r17 neutral, r18 fence storm 4x, r20/r21 hangs).
// ---------------------------------------------------------------------------
struct ProjArgs {
    const float* query; const float* key;
    const float* q_w1; const float* q_g1; const float* q_b1;
    const float* q_w2; const float* q_g2; const float* q_b2;
    const float* k_w1; const float* k_g1; const float* k_b1;
    const float* k_w2; const float* k_g2; const float* k_b2;
    const float* v_w;  const float* v_g;  const float* v_b;
    unsigned short* Qbf; unsigned short* Kbf; unsigned short* Vbf;
    float qscale;
};

__global__ __launch_bounds__(256)
void qkv_proj(ProjArgs A)
{
    __shared__ __align__(16) unsigned short Xt[64 * 128];   // 16 KB X tile
    __shared__ __align__(16) unsigned short Ct[64 * 128];   // 16 KB mid/epi

    const int t    = threadIdx.x;
    const int b    = blockIdx.y;
    const int p0   = blockIdx.x * 64;
    const int z    = blockIdx.z;            // 0: q-path, 1: k+v-path
    const int wave = t >> 6;
    const int lane = t & 63;
    const int quad = lane >> 4;
    const int l16  = lane & 15;
    const float BNRS = 0.99999500003749972f;  // 1/sqrt(1 + 1e-5)

    const float* Xg = (z == 0) ? A.query : A.key;
    const float* W1 = (z == 0) ? A.q_w1 : A.k_w1;
    const float* G1 = (z == 0) ? A.q_g1 : A.k_g1;
    const float* B1 = (z == 0) ? A.q_b1 : A.k_b1;
    const float* W2 = (z == 0) ? A.q_w2 : A.k_w2;
    const float* G2 = (z == 0) ? A.q_g2 : A.k_g2;
    const float* B2 = (z == 0) ? A.q_b2 : A.k_b2;

    // ---- T14 step 1: issue ALL X loads (HBM) into registers ----
    const float* Xb = Xg + (size_t)b * C_DIM * HW_DIM;
    float4 xa[4], xb4[4];
#pragma unroll
    for (int i = 0; i < 4; ++i) {
        int w = i * 256 + t;              // 1024 work items
        int c = (w >> 4) * 2;             // even row
        int p = (w & 15) * 4;             // 4-col group
        xa[i]  = *(const float4*)&Xb[(size_t)c * HW_DIM + p0 + p];
        xb4[i] = *(const float4*)&Xb[(size_t)(c + 1) * HW_DIM + p0 + p];
    }

    // ---- T14 step 2: W fragments (L2) — latency fills the HBM window ----
    short8 af1[2][4], af2[2][4];
#pragma unroll
    for (int mi = 0; mi < 2; ++mi) {
        int o = (wave * 2 + mi) * 16 + l16;
#pragma unroll
        for (int s = 0; s < 4; ++s) {
            af1[mi][s] = wfrag(W1 + o * C_DIM + s * 32 + quad * 8);
            af2[mi][s] = wfrag(W2 + o * C_DIM + s * 32 + quad * 8);
        }
    }

    // ---- T14 step 3: convert + LDS write (loads have landed by now) ----
#pragma unroll
    for (int i = 0; i < 4; ++i) {
        int w = i * 256 + t;
        int c = (w >> 4) * 2;
        int p = (w & 15) * 4;
        float av[4] = {xa[i].x, xa[i].y, xa[i].z, xa[i].w};
        float bv[4] = {xb4[i].x, xb4[i].y, xb4[i].z, xb4[i].w};
#pragma unroll
        for (int j = 0; j < 4; ++j) {
            int pp = p + j;
            int addr = pp * 128 + (((c >> 3) ^ (pp & 15)) * 8) + (c & 7);
            *(unsigned int*)&Xt[addr] = pack2(av[j], bv[j]);
        }
    }
    __syncthreads();

    // ---- conv1 GEMM from Xt ----
    f32x4 acc[2][4];
#pragma unroll
    for (int mi = 0; mi < 2; ++mi)
#pragma unroll
        for (int nt = 0; nt < 4; ++nt) acc[mi][nt] = (f32x4){0.f, 0.f, 0.f, 0.f};
#pragma unroll
    for (int nt = 0; nt < 4; ++nt)
#pragma unroll
        for (int s = 0; s < 4; ++s) {
            short8 bf = *(const short8*)
                &Xt[(nt * 16 + l16) * 128 + (((4 * s + quad) ^ l16) * 8)];
            acc[0][nt] = mfma_bf16(af1[0][s], bf, acc[0][nt]);
            acc[1][nt] = mfma_bf16(af1[1][s], bf, acc[1][nt]);
        }
    // BN1 + LReLU
#pragma unroll
    for (int mi = 0; mi < 2; ++mi)
#pragma unroll
        for (int r = 0; r < 4; ++r) {
            int o = (wave * 2 + mi) * 16 + quad * 4 + r;
            float sc = G1[o] * BNRS, bb = B1[o];
#pragma unroll
            for (int nt = 0; nt < 4; ++nt) {
                float y = fmaf(acc[mi][nt][r], sc, bb);
                acc[mi][nt][r] = y > 0.f ? y : 0.1f * y;
            }
        }

    // ---- mid -> Ct (B-operand swizzle) ----
#pragma unroll
    for (int mi = 0; mi < 2; ++mi)
#pragma unroll
        for (int nt = 0; nt < 4; ++nt)
#pragma unroll
            for (int r = 0; r < 4; ++r) {
                int o = (wave * 2 + mi) * 16 + quad * 4 + r;
                int p = nt * 16 + l16;
                Ct[p * 128 + (((o >> 3) ^ (p & 15)) * 8) + (o & 7)] =
                    f2bf(acc[mi][nt][r]);
            }
    __syncthreads();

    // ---- conv2 GEMM from Ct ----
#pragma unroll
    for (int mi = 0; mi < 2; ++mi)
#pragma unroll
        for (int nt = 0; nt < 4; ++nt) acc[mi][nt] = (f32x4){0.f, 0.f, 0.f, 0.f};
#pragma unroll
    for (int nt = 0; nt < 4; ++nt)
#pragma unroll
        for (int s = 0; s < 4; ++s) {
            short8 bf = *(const short8*)
                &Ct[(nt * 16 + l16) * 128 + (((4 * s + quad) ^ l16) * 8)];
            acc[0][nt] = mfma_bf16(af2[0][s], bf, acc[0][nt]);
            acc[1][nt] = mfma_bf16(af2[1][s], bf, acc[1][nt]);
        }
    // BN2 + LReLU
#pragma unroll
    for (int mi = 0; mi < 2; ++mi)
#pragma unroll
        for (int r = 0; r < 4; ++r) {
            int o = (wave * 2 + mi) * 16 + quad * 4 + r;
            float sc = G2[o] * BNRS, bb = B2[o];
#pragma unroll
            for (int nt = 0; nt < 4; ++nt) {
                float y = fmaf(acc[mi][nt][r], sc, bb);
                acc[mi][nt][r] = y > 0.f ? y : 0.1f * y;
            }
        }

    if (z == 0) {
        // ---- q epilogue: bf16 [b][pos][c] * qscale via Xt ----
        float os = A.qscale;
#pragma unroll
        for (int mi = 0; mi < 2; ++mi)
#pragma unroll
            for (int nt = 0; nt < 4; ++nt)
#pragma unroll
                for (int r = 0; r < 4; ++r) {
                    int o = (wave * 2 + mi) * 16 + quad * 4 + r;
                    int p = nt * 16 + l16;
                    Xt[p * 128 + (((o >> 3) ^ (p & 15)) * 8) + (o & 7)] =
                        f2bf(acc[mi][nt][r] * os);
                }
        __syncthreads();
#pragma unroll
        for (int i = 0; i < 4; ++i) {
            int idx = t + 256 * i;
            int p = idx >> 4, ch = idx & 15;
            uint4 v = *(const uint4*)&Xt[p * 128 + ((ch ^ (p & 15)) * 8)];
            *(uint4*)&A.Qbf[((size_t)b * HW_DIM + p0 + p) * C_DIM + ch * 8] = v;
        }
        return;
    }

    // ---- k epilogue via Ct (Xt must survive for v-conv) ----
    __syncthreads();   // all conv2 reads of Ct done
#pragma unroll
    for (int mi = 0; mi < 2; ++mi)
#pragma unroll
        for (int nt = 0; nt < 4; ++nt)
#pragma unroll
            for (int r = 0; r < 4; ++r) {
                int o = (wave * 2 + mi) * 16 + quad * 4 + r;
                int p = nt * 16 + l16;
                Ct[p * 128 + (((o >> 3) ^ (p & 15)) * 8) + (o & 7)] =
                    f2bf(acc[mi][nt][r]);
            }
    __syncthreads();
#pragma unroll
    for (int i = 0; i < 4; ++i) {
        int idx = t + 256 * i;
        int p = idx >> 4, ch = idx & 15;
        uint4 v = *(const uint4*)&Ct[p * 128 + ((ch ^ (p & 15)) * 8)];
        *(uint4*)&A.Kbf[((size_t)b * HW_DIM + p0 + p) * C_DIM + ch * 8] = v;
    }

    // ---- v-conv from the SAME Xt ----
    short8 afv[2][4];
#pragma unroll
    for (int mi = 0; mi < 2; ++mi) {
        int o = (wave * 2 + mi) * 16 + l16;
#pragma unroll
        for (int s = 0; s < 4; ++s)
            afv[mi][s] = wfrag(A.v_w + o * C_DIM + s * 32 + quad * 8);
    }
#pragma unroll
    for (int mi = 0; mi < 2; ++mi)
#pragma unroll
        for (int nt = 0; nt < 4; ++nt) acc[mi][nt] = (f32x4){0.f, 0.f, 0.f, 0.f};
#pragma unroll
    for (int nt = 0; nt < 4; ++nt)
#pragma unroll
        for (int s = 0; s < 4; ++s) {
            short8 bf = *(const short8*)
                &Xt[(nt * 16 + l16) * 128 + (((4 * s + quad) ^ l16) * 8)];
            acc[0][nt] = mfma_bf16(afv[0][s], bf, acc[0][nt]);
            acc[1][nt] = mfma_bf16(afv[1][s], bf, acc[1][nt]);
        }
#pragma unroll
    for (int mi = 0; mi < 2; ++mi)
#pragma unroll
        for (int r = 0; r < 4; ++r) {
            int o = (wave * 2 + mi) * 16 + quad * 4 + r;
            float sc = A.v_g[o] * BNRS, bb = A.v_b[o];
#pragma unroll
            for (int nt = 0; nt < 4; ++nt) {
                float y = fmaf(acc[mi][nt][r], sc, bb);
                acc[mi][nt][r] = y > 0.f ? y : 0.1f * y;
            }
        }

    // ---- v epilogue: bf16 [b][c][pos] via Ct ----
    __syncthreads();   // Kbf-store reads of Ct done
#pragma unroll
    for (int mi = 0; mi < 2; ++mi)
#pragma unroll
        for (int nt = 0; nt < 4; ++nt)
#pragma unroll
            for (int r = 0; r < 4; ++r) {
                int o = (wave * 2 + mi) * 16 + quad * 4 + r;
                int p = nt * 16 + l16;
                Ct[o * 64 + (((p >> 3) ^ (o & 7)) * 8) + (p & 7)] =
                    f2bf(acc[mi][nt][r]);
            }
    __syncthreads();
#pragma unroll
    for (int i = 0; i < 4; ++i) {              // all 1024 chunks (r14 fix)
        int idx = t + 256 * i;
        int o = idx >> 3, ch = idx & 7;
        uint4 v = *(const uint4*)&Ct[o * 64 + ((ch ^ (o & 7)) * 8)];
        *(uint4*)&A.Vbf[((size_t)b * C_DIM + o) * HW_DIM + p0 + ch * 8] = v;
    }
}

// ---------------------------------------------------------------------------
// Flash attention (r22 pipeline + r23 interleaved partial layout — the
// best-measured flash at 54.9-55.8 µs, 0 bank conflicts, no spill).
// ---------------------------------------------------------------------------
template <int NSPLIT>
__global__ __launch_bounds__(256, 2)
void flash_attn(const unsigned short* __restrict__ Q,
                const unsigned short* __restrict__ K,
                const unsigned short* __restrict__ V,
                unsigned short* __restrict__ Pint,
                float* __restrict__ Lint)
{
    __shared__ __align__(16) unsigned short TM[2][16384];     // 64 KB dbuf
    __shared__ __align__(16) unsigned short Plds[4][16][64];  // 8 KB swizzled

    const int t    = threadIdx.x;
    const int wave = t >> 6;
    const int lane = t & 63;
    const int quad = lane >> 4;
    const int l16  = lane & 15;

    constexpr int KS_BITS = (NSPLIT == 8) ? 3 : 2;
    const int bid  = blockIdx.x;
    const int ks   = bid & (NSPLIT - 1);        // = XCD under round-robin
    const int fb   = (bid >> KS_BITS) & 1;
    const int qblk = bid >> (KS_BITS + 1);      // 0..31
    const int q0   = qblk * 192 + wave * 48;
    const int kbeg = ks * (HW_DIM / NSPLIT);

    const unsigned short* Qb = Q + (size_t)fb * HW_DIM * C_DIM;
    const unsigned short* Kb = K + (size_t)fb * HW_DIM * C_DIM;
    const unsigned short* Vb = V + (size_t)fb * C_DIM * HW_DIM;

    short8 qf[3][4];
#pragma unroll
    for (int rt = 0; rt < 3; ++rt)
#pragma unroll
        for (int s = 0; s < 4; ++s)
            qf[rt][s] = *(const short8*)
                &Qb[(size_t)(q0 + rt * 16 + l16) * C_DIM + s * 32 + quad * 8];

    f32x4 O[3][8];
#pragma unroll
    for (int rt = 0; rt < 3; ++rt)
#pragma unroll
        for (int h = 0; h < 8; ++h) O[rt][h] = (f32x4){0.f, 0.f, 0.f, 0.f};
    float lsum[3][4] = {{0,0,0,0},{0,0,0,0},{0,0,0,0}};

    int koff[4], voff[4];
#pragma unroll
    for (int j = 0; j < 4; ++j) {
        int ci = t + 256 * j;
        int kr = ci >> 4, kc = ci & 15;
        koff[j] = kr * C_DIM + ((kc ^ (kr & 15)) << 3);
        int vr = ci >> 3, vc = ci & 7;
        voff[j] = vr * HW_DIM + ((vc ^ (vr & 7)) << 3);
    }

    const int NIT = (HW_DIM / NSPLIT) / 64;

    // prologue: stage tile 0 into buf 0
    {
        const unsigned short* Ksrc = Kb + (size_t)kbeg * C_DIM;
        const unsigned short* Vsrc = Vb + kbeg;
        unsigned short* Kt = TM[0];
        unsigned short* Vt = TM[0] + 8192;
#pragma unroll
        for (int j = 0; j < 4; ++j) {
            int ci = t + 256 * j;
            gload16(Ksrc + koff[j], &Kt[ci * 8]);
            gload16(Vsrc + voff[j], &Vt[ci * 8]);
        }
    }
    __syncthreads();

    int cur = 0;
    for (int it = 0; it < NIT; ++it) {
        if (it + 1 < NIT) {
            const int kb2 = kbeg + (it + 1) * 64;
            const unsigned short* Ksrc = Kb + (size_t)kb2 * C_DIM;
            const unsigned short* Vsrc = Vb + kb2;
            unsigned short* Kt2 = TM[cur ^ 1];
            unsigned short* Vt2 = TM[cur ^ 1] + 8192;
#pragma unroll
            for (int j = 0; j < 4; ++j) {
                int ci = t + 256 * j;
                gload16(Ksrc + koff[j], &Kt2[ci * 8]);
                gload16(Vsrc + voff[j], &Vt2[ci * 8]);
            }
        }

        unsigned short* Kt = TM[cur];
        unsigned short* Vt = TM[cur] + 8192;

        f32x4 S[3][4];
#pragma unroll
        for (int rt = 0; rt < 3; ++rt)
#pragma unroll
            for (int n = 0; n < 4; ++n) S[rt][n] = (f32x4){0.f, 0.f, 0.f, 0.f};
#pragma unroll
        for (int n = 0; n < 4; ++n)
#pragma unroll
            for (int s = 0; s < 4; ++s) {
                short8 kf = *(const short8*)
                    &Kt[(size_t)(n * 16 + l16) * 128 + (((4 * s + quad) ^ l16) * 8)];
                S[0][n] = mfma_bf16(qf[0][s], kf, S[0][n]);
                S[1][n] = mfma_bf16(qf[1][s], kf, S[1][n]);
                S[2][n] = mfma_bf16(qf[2][s], kf, S[2][n]);
            }

        short8 pa[3][2];
#pragma unroll
        for (int rt = 0; rt < 3; ++rt) {
#pragma unroll
            for (int n = 0; n < 4; ++n)
#pragma unroll
                for (int r = 0; r < 4; ++r) {
                    float e = __builtin_amdgcn_exp2f(S[rt][n][r]);
                    lsum[rt][r] += e;
                    int row = quad * 4 + r;
                    Plds[wave][row][(((n * 2 + (l16 >> 3)) ^ (row & 7)) << 3) | (l16 & 7)] =
                        f2bf(e);
                }
            pa[rt][0] = *(const short8*)&Plds[wave][l16][((quad       ^ (l16 & 7)) << 3)];
            pa[rt][1] = *(const short8*)&Plds[wave][l16][(((4 + quad) ^ (l16 & 7)) << 3)];
        }

        const int m = l16 & 7;
#pragma unroll
        for (int h = 0; h < 8; ++h) {
            short8 v0 = *(const short8*)&Vt[(size_t)(h * 16 + l16) * 64 + ((quad ^ m) * 8)];
            short8 v1 = *(const short8*)&Vt[(size_t)(h * 16 + l16) * 64 + (((quad + 4) ^ m) * 8)];
            O[0][h] = mfma_bf16(pa[0][0], v0, O[0][h]);
            O[0][h] = mfma_bf16(pa[0][1], v1, O[0][h]);
            O[1][h] = mfma_bf16(pa[1][0], v0, O[1][h]);
            O[1][h] = mfma_bf16(pa[1][1], v1, O[1][h]);
            O[2][h] = mfma_bf16(pa[2][0], v0, O[2][h]);
            O[2][h] = mfma_bf16(pa[2][1], v1, O[2][h]);
        }

        __syncthreads();
        cur ^= 1;
    }

#pragma unroll
    for (int off = 1; off < 16; off <<= 1)
#pragma unroll
        for (int rt = 0; rt < 3; ++rt)
#pragma unroll
            for (int r = 0; r < 4; ++r)
                lsum[rt][r] += __shfl_xor(lsum[rt][r], off, 64);

    // ---- write P/L partials (interleaved layout) ----
#pragma unroll
    for (int rt = 0; rt < 3; ++rt)
#pragma unroll
        for (int r = 0; r < 4; ++r) {
            int lrow = wave * 48 + rt * 16 + quad * 4 + r;
            size_t row = (size_t)fb * HW_DIM + qblk * 192 + lrow;
            if (l16 == 0) Lint[row * NSPLIT + ks] = lsum[rt][r];
#pragma unroll
            for (int h = 0; h < 8; ++h)
                Pint[row * (NSPLIT * C_DIM) + ks * C_DIM + h * 16 + l16] =
                    f2bf(O[rt][h][r]);
        }
}

// ---------------------------------------------------------------------------
// Launch C: combine + out-conv + residual (T14 load batching; best-proven).
// ---------------------------------------------------------------------------
template <int NPARTS>
__global__ __launch_bounds__(256)
void combine_out(const unsigned short* __restrict__ Pint,
                 const float* __restrict__ Lint,
                 const float* __restrict__ OW,
                 const float* __restrict__ OG,
                 const float* __restrict__ OB,
                 const float* __restrict__ RESID,
                 float* __restrict__ OUT)
{
    __shared__ __align__(16) unsigned short Xt[32 * 128];   // 8 KB
    __shared__ float invl[32];

    const int t    = threadIdx.x;
    const int b    = blockIdx.y;
    const int p0   = blockIdx.x * 32;
    const int wave = t >> 6;
    const int lane = t & 63;
    const int quad = lane >> 4;
    const int l16  = lane & 15;
    const float BNRS = 0.99999500003749972f;

    // ---- T14: issue ALL partial loads first ----
    uint4 pv[2][NPARTS];
#pragma unroll
    for (int i = 0; i < 2; ++i) {
        int idx = t + 256 * i;
        int p = idx >> 4, ch = idx & 15;
        size_t row = (size_t)b * HW_DIM + p0 + p;
        size_t base = row * (NPARTS * C_DIM) + ch * 8;
#pragma unroll
        for (int pr = 0; pr < NPARTS; ++pr)
            pv[i][pr] = *(const uint4*)&Pint[base + (size_t)pr * C_DIM];
    }

    // ---- W fragments (L2) while partials stream ----
    short8 af[2][4];
#pragma unroll
    for (int mi = 0; mi < 2; ++mi) {
        int o = (wave * 2 + mi) * 16 + l16;
#pragma unroll
        for (int s = 0; s < 4; ++s)
            af[mi][s] = wfrag(OW + o * C_DIM + s * 32 + quad * 8);
    }

    if (t < 32) {
        size_t row = (size_t)b * HW_DIM + p0 + t;
        float s = 0.f;
#pragma unroll
        for (int pr = 0; pr < NPARTS; ++pr)
            s += Lint[row * NPARTS + pr];
        invl[t] = 1.0f / s;
    }
    __syncthreads();

    // ---- accumulate + normalize -> Xt ----
#pragma unroll
    for (int i = 0; i < 2; ++i) {
        int idx = t + 256 * i;
        int p = idx >> 4, ch = idx & 15;
        float acc8[8] = {0.f, 0.f, 0.f, 0.f, 0.f, 0.f, 0.f, 0.f};
#pragma unroll
        for (int pr = 0; pr < NPARTS; ++pr) {
            const unsigned int* ap = (const unsigned int*)&pv[i][pr];
#pragma unroll
            for (int j = 0; j < 4; ++j) {
                acc8[2 * j]     += bf2f((unsigned short)(ap[j] & 0xFFFF));
                acc8[2 * j + 1] += bf2f((unsigned short)(ap[j] >> 16));
            }
        }
        float s = invl[p];
        unsigned int w[4];
#pragma unroll
        for (int j = 0; j < 4; ++j)
            w[j] = pack2(acc8[2 * j] * s, acc8[2 * j + 1] * s);
        *(uint4*)&Xt[p * 128 + ((ch ^ (p & 15)) * 8)] = *(uint4*)w;
    }
    __syncthreads();

    f32x4 acc[2][2];
#pragma unroll
    for (int mi = 0; mi < 2; ++mi)
#pragma unroll
        for (int nt = 0; nt < 2; ++nt) acc[mi][nt] = (f32x4){0.f, 0.f, 0.f, 0.f};
#pragma unroll
    for (int nt = 0; nt < 2; ++nt)
#pragma unroll
        for (int s = 0; s < 4; ++s) {
            short8 bf = *(const short8*)
                &Xt[(nt * 16 + l16) * 128 + (((4 * s + quad) ^ l16) * 8)];
            acc[0][nt] = mfma_bf16(af[0][s], bf, acc[0][nt]);
            acc[1][nt] = mfma_bf16(af[1][s], bf, acc[1][nt]);
        }

#pragma unroll
    for (int mi = 0; mi < 2; ++mi)
#pragma unroll
        for (int r = 0; r < 4; ++r) {
            int o = (wave * 2 + mi) * 16 + quad * 4 + r;
            float sc = OG[o] * BNRS, bb = OB[o];
#pragma unroll
            for (int nt = 0; nt < 2; ++nt) {
                float y = fmaf(acc[mi][nt][r], sc, bb);
                y = y > 0.f ? y : 0.1f * y;
                size_t g = ((size_t)b * C_DIM + o) * HW_DIM + p0 + nt * 16 + l16;
                OUT[g] = y + RESID[g];
            }
        }
}

// ---------------------------------------------------------------------------
extern "C" void kernel_launch(void* const* d_in, const int* in_sizes, int n_in,
                              void* d_out, int out_size, void* d_ws, size_t ws_size,
                              hipStream_t stream)
{
    // Workspace: [ Pint: nsplit*3145728 B ][ Qbf ][ Kbf ][ Vbf ][ Lint: nsplit*49152 B ]
    const size_t PPART = (size_t)2 * HW_DIM * C_DIM * 2;  // 3,145,728 B
    const size_t LPART = (size_t)2 * HW_DIM * 4;          // 49,152 B
    const int nsplit = (ws_size >= 11 * PPART + 8 * LPART) ? 8 : 4;

    char* ws = (char*)d_ws;
    unsigned short* Pint = (unsigned short*)ws;
    unsigned short* Qbf = (unsigned short*)(ws + (size_t)nsplit * PPART);
    unsigned short* Kbf = (unsigned short*)(ws + (size_t)nsplit * PPART + PPART);
    unsigned short* Vbf = (unsigned short*)(ws + (size_t)nsplit * PPART + 2 * PPART);
    float*          Lint = (float*)(ws + (size_t)nsplit * PPART + 3 * PPART);
    float* outp = (float*)d_out;

    // Launch A: QKV projections, key staged once. Grid (96,2,2)=384 blocks.
    {
        ProjArgs pa;
        pa.query = (const float*)d_in[0];
        pa.key   = (const float*)d_in[1];
        pa.q_w1 = (const float*)d_in[2];  pa.q_g1 = (const float*)d_in[3];
        pa.q_b1 = (const float*)d_in[4];
        pa.q_w2 = (const float*)d_in[5];  pa.q_g2 = (const float*)d_in[6];
        pa.q_b2 = (const float*)d_in[7];
        pa.k_w1 = (const float*)d_in[8];  pa.k_g1 = (const float*)d_in[9];
        pa.k_b1 = (const float*)d_in[10];
        pa.k_w2 = (const float*)d_in[11]; pa.k_g2 = (const float*)d_in[12];
        pa.k_b2 = (const float*)d_in[13];
        pa.v_w  = (const float*)d_in[14]; pa.v_g  = (const float*)d_in[15];
        pa.v_b  = (const float*)d_in[16];
        pa.Qbf = Qbf; pa.Kbf = Kbf; pa.Vbf = Vbf;
        pa.qscale = 0.08838834764831845f * 1.44269504088896340f;
        hipLaunchKernelGGL(qkv_proj, dim3(HW_DIM / 64, 2, 2), dim3(256),
                           0, stream, pa);
    }

    // Flash: dbuf pipeline, interleaved P/L writes. 512 blocks (2/CU), rt=3.
    if (nsplit == 8) {
        hipLaunchKernelGGL(HIP_KERNEL_NAME(flash_attn<8>),
                           dim3(2 * (HW_DIM / 192) * 8), dim3(256),
                           0, stream, Qbf, Kbf, Vbf, Pint, Lint);
    } else {
        hipLaunchKernelGGL(HIP_KERNEL_NAME(flash_attn<4>),
                           dim3(2 * (HW_DIM / 192) * 4), dim3(256),
                           0, stream, Qbf, Kbf, Vbf, Pint, Lint);
    }

    // Launch C: combine (batched streaming reads) + out-conv + residual.
    {
        const float* o_w = (const float*)d_in[17];
        const float* o_g = (const float*)d_in[18];
        const float* o_b = (const float*)d_in[19];
        if (nsplit == 8) {
            hipLaunchKernelGGL(HIP_KERNEL_NAME(combine_out<8>),
                               dim3(HW_DIM / 32, 2), dim3(256), 0, stream,
                               Pint, Lint, o_w, o_g, o_b,
                               (const float*)d_in[0], outp);
        } else {
            hipLaunchKernelGGL(HIP_KERNEL_NAME(combine_out<4>),
                               dim3(HW_DIM / 32, 2), dim3(256), 0, stream,
                               Pint, Lint, o_w, o_g, o_b,
                               (const float*)d_in[0], outp);
        }
    }
}

// Round 15
// 167.604 us; speedup vs baseline: 1.0114x; 1.0006x over previous
//
#include <hip/hip_runtime.h>

#define C_DIM 128
#define HW_DIM 6144

typedef __attribute__((ext_vector_type(8))) short short8;
typedef __attribute__((ext_vector_type(4))) float f32x4;

static __device__ __forceinline__ unsigned short f2bf(float x) {
    unsigned int u = __builtin_bit_cast(unsigned int, x);
    u = (u + 0x7FFFu + ((u >> 16) & 1u)) >> 16;
    return (unsigned short)u;
}
static __device__ __forceinline__ float bf2f(unsigned short u) {
    unsigned int x = ((unsigned int)u) << 16;
    return __builtin_bit_cast(float, x);
}
static __device__ __forceinline__ unsigned int pack2(float a, float b) {
    return (unsigned int)f2bf(a) | ((unsigned int)f2bf(b) << 16);
}
static __device__ __forceinline__ f32x4 mfma_bf16(short8 a, short8 b, f32x4 c) {
    return __builtin_amdgcn_mfma_f32_16x16x32_bf16(a, b, c, 0, 0, 0);
}
// async global->LDS, 16B per lane; LDS dest linear, global source pre-swizzled.
static __device__ __forceinline__ void gload16(const unsigned short* g,
                                               unsigned short* l) {
    __builtin_amdgcn_global_load_lds(
        (const __attribute__((address_space(1))) unsigned int*)g,
        (__attribute__((address_space(3))) unsigned int*)l, 16, 0, 0);
}
// MFMA A-fragment (bf16) directly from global fp32 W[o][c].
static __device__ __forceinline__ short8 wfrag(const float* Wrow) {
    float4 a = *(const float4*)Wrow;
    float4 b = *(const float4*)(Wrow + 4);
    unsigned int u[4] = {pack2(a.x, a.y), pack2(a.z, a.w),
                         pack2(b.x, b.y), pack2(b.z, b.w)};
    return *(const short8*)u;
}

// ---------------------------------------------------------------------------
// FINAL (r29 == r28 == r24, best-measured twice: 168.3 / 167.7 µs).
// Session: 210.7 -> 167.7 µs (-20.4%).
//   A: fused q/k double-conv + v-conv, key staged once, T14 async-stage
//      split (issue all HBM loads -> W frags in L2 window -> convert).
//   flash: KVBLK=64, rt=3, double-buffered single-barrier pipeline
//      (prefetch issued at iter top, ONE barrier drains it after compute),
//      interleaved P/L partial layout for streaming combine. 512 blocks,
//      2/CU, 0 bank conflicts, VGPR 128 no spill.
//   C: interleaved-partial streaming combine + out-conv + residual,
//      T14 load batching, N=32 tiles (384 blocks).
// Characterized plateau (measured, not conjecture):
//   - flash is latency-structure bound (MfmaUtil 28%, HBM 10%, 2 waves/SIMD);
//     KVBLK=32 occupancy fix = structural 4-way LDS conflict (r25, +5.3M);
//     setprio/stagger = null (r26); next lever is the in-register-softmax
//     multi-technique rewrite — high regression risk, not attempted.
//   - non-flash ~114 µs is dominated by per-replay fixed cost; whole-graph
//     fusion failed 3 ways (r18 fence storm 4x, r20 coop-launch no-op,
//     r21 grid-barrier hang). A-balance/combine micro-opts all sub-noise.
// ---------------------------------------------------------------------------
struct ProjArgs {
    const float* query; const float* key;
    const float* q_w1; const float* q_g1; const float* q_b1;
    const float* q_w2; const float* q_g2; const float* q_b2;
    const float* k_w1; const float* k_g1; const float* k_b1;
    const float* k_w2; const float* k_g2; const float* k_b2;
    const float* v_w;  const float* v_g;  const float* v_b;
    unsigned short* Qbf; unsigned short* Kbf; unsigned short* Vbf;
    float qscale;
};

__global__ __launch_bounds__(256)
void qkv_proj(ProjArgs A)
{
    __shared__ __align__(16) unsigned short Xt[64 * 128];   // 16 KB X tile
    __shared__ __align__(16) unsigned short Ct[64 * 128];   // 16 KB mid/epi

    const int t    = threadIdx.x;
    const int b    = blockIdx.y;
    const int p0   = blockIdx.x * 64;
    const int z    = blockIdx.z;            // 0: q-path, 1: k+v-path
    const int wave = t >> 6;
    const int lane = t & 63;
    const int quad = lane >> 4;
    const int l16  = lane & 15;
    const float BNRS = 0.99999500003749972f;  // 1/sqrt(1 + 1e-5)

    const float* Xg = (z == 0) ? A.query : A.key;
    const float* W1 = (z == 0) ? A.q_w1 : A.k_w1;
    const float* G1 = (z == 0) ? A.q_g1 : A.k_g1;
    const float* B1 = (z == 0) ? A.q_b1 : A.k_b1;
    const float* W2 = (z == 0) ? A.q_w2 : A.k_w2;
    const float* G2 = (z == 0) ? A.q_g2 : A.k_g2;
    const float* B2 = (z == 0) ? A.q_b2 : A.k_b2;

    // ---- T14 step 1: issue ALL X loads (HBM) into registers ----
    const float* Xb = Xg + (size_t)b * C_DIM * HW_DIM;
    float4 xa[4], xb4[4];
#pragma unroll
    for (int i = 0; i < 4; ++i) {
        int w = i * 256 + t;              // 1024 work items
        int c = (w >> 4) * 2;             // even row
        int p = (w & 15) * 4;             // 4-col group
        xa[i]  = *(const float4*)&Xb[(size_t)c * HW_DIM + p0 + p];
        xb4[i] = *(const float4*)&Xb[(size_t)(c + 1) * HW_DIM + p0 + p];
    }

    // ---- T14 step 2: W fragments (L2) — latency fills the HBM window ----
    short8 af1[2][4], af2[2][4];
#pragma unroll
    for (int mi = 0; mi < 2; ++mi) {
        int o = (wave * 2 + mi) * 16 + l16;
#pragma unroll
        for (int s = 0; s < 4; ++s) {
            af1[mi][s] = wfrag(W1 + o * C_DIM + s * 32 + quad * 8);
            af2[mi][s] = wfrag(W2 + o * C_DIM + s * 32 + quad * 8);
        }
    }

    // ---- T14 step 3: convert + LDS write (loads have landed by now) ----
#pragma unroll
    for (int i = 0; i < 4; ++i) {
        int w = i * 256 + t;
        int c = (w >> 4) * 2;
        int p = (w & 15) * 4;
        float av[4] = {xa[i].x, xa[i].y, xa[i].z, xa[i].w};
        float bv[4] = {xb4[i].x, xb4[i].y, xb4[i].z, xb4[i].w};
#pragma unroll
        for (int j = 0; j < 4; ++j) {
            int pp = p + j;
            int addr = pp * 128 + (((c >> 3) ^ (pp & 15)) * 8) + (c & 7);
            *(unsigned int*)&Xt[addr] = pack2(av[j], bv[j]);
        }
    }
    __syncthreads();

    // ---- conv1 GEMM from Xt ----
    f32x4 acc[2][4];
#pragma unroll
    for (int mi = 0; mi < 2; ++mi)
#pragma unroll
        for (int nt = 0; nt < 4; ++nt) acc[mi][nt] = (f32x4){0.f, 0.f, 0.f, 0.f};
#pragma unroll
    for (int nt = 0; nt < 4; ++nt)
#pragma unroll
        for (int s = 0; s < 4; ++s) {
            short8 bf = *(const short8*)
                &Xt[(nt * 16 + l16) * 128 + (((4 * s + quad) ^ l16) * 8)];
            acc[0][nt] = mfma_bf16(af1[0][s], bf, acc[0][nt]);
            acc[1][nt] = mfma_bf16(af1[1][s], bf, acc[1][nt]);
        }
    // BN1 + LReLU
#pragma unroll
    for (int mi = 0; mi < 2; ++mi)
#pragma unroll
        for (int r = 0; r < 4; ++r) {
            int o = (wave * 2 + mi) * 16 + quad * 4 + r;
            float sc = G1[o] * BNRS, bb = B1[o];
#pragma unroll
            for (int nt = 0; nt < 4; ++nt) {
                float y = fmaf(acc[mi][nt][r], sc, bb);
                acc[mi][nt][r] = y > 0.f ? y : 0.1f * y;
            }
        }

    // ---- mid -> Ct (B-operand swizzle) ----
#pragma unroll
    for (int mi = 0; mi < 2; ++mi)
#pragma unroll
        for (int nt = 0; nt < 4; ++nt)
#pragma unroll
            for (int r = 0; r < 4; ++r) {
                int o = (wave * 2 + mi) * 16 + quad * 4 + r;
                int p = nt * 16 + l16;
                Ct[p * 128 + (((o >> 3) ^ (p & 15)) * 8) + (o & 7)] =
                    f2bf(acc[mi][nt][r]);
            }
    __syncthreads();

    // ---- conv2 GEMM from Ct ----
#pragma unroll
    for (int mi = 0; mi < 2; ++mi)
#pragma unroll
        for (int nt = 0; nt < 4; ++nt) acc[mi][nt] = (f32x4){0.f, 0.f, 0.f, 0.f};
#pragma unroll
    for (int nt = 0; nt < 4; ++nt)
#pragma unroll
        for (int s = 0; s < 4; ++s) {
            short8 bf = *(const short8*)
                &Ct[(nt * 16 + l16) * 128 + (((4 * s + quad) ^ l16) * 8)];
            acc[0][nt] = mfma_bf16(af2[0][s], bf, acc[0][nt]);
            acc[1][nt] = mfma_bf16(af2[1][s], bf, acc[1][nt]);
        }
    // BN2 + LReLU
#pragma unroll
    for (int mi = 0; mi < 2; ++mi)
#pragma unroll
        for (int r = 0; r < 4; ++r) {
            int o = (wave * 2 + mi) * 16 + quad * 4 + r;
            float sc = G2[o] * BNRS, bb = B2[o];
#pragma unroll
            for (int nt = 0; nt < 4; ++nt) {
                float y = fmaf(acc[mi][nt][r], sc, bb);
                acc[mi][nt][r] = y > 0.f ? y : 0.1f * y;
            }
        }

    if (z == 0) {
        // ---- q epilogue: bf16 [b][pos][c] * qscale via Xt ----
        float os = A.qscale;
#pragma unroll
        for (int mi = 0; mi < 2; ++mi)
#pragma unroll
            for (int nt = 0; nt < 4; ++nt)
#pragma unroll
                for (int r = 0; r < 4; ++r) {
                    int o = (wave * 2 + mi) * 16 + quad * 4 + r;
                    int p = nt * 16 + l16;
                    Xt[p * 128 + (((o >> 3) ^ (p & 15)) * 8) + (o & 7)] =
                        f2bf(acc[mi][nt][r] * os);
                }
        __syncthreads();
#pragma unroll
        for (int i = 0; i < 4; ++i) {
            int idx = t + 256 * i;
            int p = idx >> 4, ch = idx & 15;
            uint4 v = *(const uint4*)&Xt[p * 128 + ((ch ^ (p & 15)) * 8)];
            *(uint4*)&A.Qbf[((size_t)b * HW_DIM + p0 + p) * C_DIM + ch * 8] = v;
        }
        return;
    }

    // ---- k epilogue via Ct (Xt must survive for v-conv) ----
    __syncthreads();   // all conv2 reads of Ct done
#pragma unroll
    for (int mi = 0; mi < 2; ++mi)
#pragma unroll
        for (int nt = 0; nt < 4; ++nt)
#pragma unroll
            for (int r = 0; r < 4; ++r) {
                int o = (wave * 2 + mi) * 16 + quad * 4 + r;
                int p = nt * 16 + l16;
                Ct[p * 128 + (((o >> 3) ^ (p & 15)) * 8) + (o & 7)] =
                    f2bf(acc[mi][nt][r]);
            }
    __syncthreads();
#pragma unroll
    for (int i = 0; i < 4; ++i) {
        int idx = t + 256 * i;
        int p = idx >> 4, ch = idx & 15;
        uint4 v = *(const uint4*)&Ct[p * 128 + ((ch ^ (p & 15)) * 8)];
        *(uint4*)&A.Kbf[((size_t)b * HW_DIM + p0 + p) * C_DIM + ch * 8] = v;
    }

    // ---- v-conv from the SAME Xt ----
    short8 afv[2][4];
#pragma unroll
    for (int mi = 0; mi < 2; ++mi) {
        int o = (wave * 2 + mi) * 16 + l16;
#pragma unroll
        for (int s = 0; s < 4; ++s)
            afv[mi][s] = wfrag(A.v_w + o * C_DIM + s * 32 + quad * 8);
    }
#pragma unroll
    for (int mi = 0; mi < 2; ++mi)
#pragma unroll
        for (int nt = 0; nt < 4; ++nt) acc[mi][nt] = (f32x4){0.f, 0.f, 0.f, 0.f};
#pragma unroll
    for (int nt = 0; nt < 4; ++nt)
#pragma unroll
        for (int s = 0; s < 4; ++s) {
            short8 bf = *(const short8*)
                &Xt[(nt * 16 + l16) * 128 + (((4 * s + quad) ^ l16) * 8)];
            acc[0][nt] = mfma_bf16(afv[0][s], bf, acc[0][nt]);
            acc[1][nt] = mfma_bf16(afv[1][s], bf, acc[1][nt]);
        }
#pragma unroll
    for (int mi = 0; mi < 2; ++mi)
#pragma unroll
        for (int r = 0; r < 4; ++r) {
            int o = (wave * 2 + mi) * 16 + quad * 4 + r;
            float sc = A.v_g[o] * BNRS, bb = A.v_b[o];
#pragma unroll
            for (int nt = 0; nt < 4; ++nt) {
                float y = fmaf(acc[mi][nt][r], sc, bb);
                acc[mi][nt][r] = y > 0.f ? y : 0.1f * y;
            }
        }

    // ---- v epilogue: bf16 [b][c][pos] via Ct ----
    __syncthreads();   // Kbf-store reads of Ct done
#pragma unroll
    for (int mi = 0; mi < 2; ++mi)
#pragma unroll
        for (int nt = 0; nt < 4; ++nt)
#pragma unroll
            for (int r = 0; r < 4; ++r) {
                int o = (wave * 2 + mi) * 16 + quad * 4 + r;
                int p = nt * 16 + l16;
                Ct[o * 64 + (((p >> 3) ^ (o & 7)) * 8) + (p & 7)] =
                    f2bf(acc[mi][nt][r]);
            }
    __syncthreads();
#pragma unroll
    for (int i = 0; i < 4; ++i) {              // all 1024 chunks (r14 fix)
        int idx = t + 256 * i;
        int o = idx >> 3, ch = idx & 7;
        uint4 v = *(const uint4*)&Ct[o * 64 + ((ch ^ (o & 7)) * 8)];
        *(uint4*)&A.Vbf[((size_t)b * C_DIM + o) * HW_DIM + p0 + ch * 8] = v;
    }
}

// ---------------------------------------------------------------------------
// Flash attention (double-buffered single-barrier pipeline + interleaved
// partial layout — best-measured flash at 53.9-55.8 µs, 0 conflicts).
// ---------------------------------------------------------------------------
template <int NSPLIT>
__global__ __launch_bounds__(256, 2)
void flash_attn(const unsigned short* __restrict__ Q,
                const unsigned short* __restrict__ K,
                const unsigned short* __restrict__ V,
                unsigned short* __restrict__ Pint,
                float* __restrict__ Lint)
{
    __shared__ __align__(16) unsigned short TM[2][16384];     // 64 KB dbuf
    __shared__ __align__(16) unsigned short Plds[4][16][64];  // 8 KB swizzled

    const int t    = threadIdx.x;
    const int wave = t >> 6;
    const int lane = t & 63;
    const int quad = lane >> 4;
    const int l16  = lane & 15;

    constexpr int KS_BITS = (NSPLIT == 8) ? 3 : 2;
    const int bid  = blockIdx.x;
    const int ks   = bid & (NSPLIT - 1);        // = XCD under round-robin
    const int fb   = (bid >> KS_BITS) & 1;
    const int qblk = bid >> (KS_BITS + 1);      // 0..31
    const int q0   = qblk * 192 + wave * 48;
    const int kbeg = ks * (HW_DIM / NSPLIT);

    const unsigned short* Qb = Q + (size_t)fb * HW_DIM * C_DIM;
    const unsigned short* Kb = K + (size_t)fb * HW_DIM * C_DIM;
    const unsigned short* Vb = V + (size_t)fb * C_DIM * HW_DIM;

    short8 qf[3][4];
#pragma unroll
    for (int rt = 0; rt < 3; ++rt)
#pragma unroll
        for (int s = 0; s < 4; ++s)
            qf[rt][s] = *(const short8*)
                &Qb[(size_t)(q0 + rt * 16 + l16) * C_DIM + s * 32 + quad * 8];

    f32x4 O[3][8];
#pragma unroll
    for (int rt = 0; rt < 3; ++rt)
#pragma unroll
        for (int h = 0; h < 8; ++h) O[rt][h] = (f32x4){0.f, 0.f, 0.f, 0.f};
    float lsum[3][4] = {{0,0,0,0},{0,0,0,0},{0,0,0,0}};

    int koff[4], voff[4];
#pragma unroll
    for (int j = 0; j < 4; ++j) {
        int ci = t + 256 * j;
        int kr = ci >> 4, kc = ci & 15;
        koff[j] = kr * C_DIM + ((kc ^ (kr & 15)) << 3);
        int vr = ci >> 3, vc = ci & 7;
        voff[j] = vr * HW_DIM + ((vc ^ (vr & 7)) << 3);
    }

    const int NIT = (HW_DIM / NSPLIT) / 64;

    // prologue: stage tile 0 into buf 0
    {
        const unsigned short* Ksrc = Kb + (size_t)kbeg * C_DIM;
        const unsigned short* Vsrc = Vb + kbeg;
        unsigned short* Kt = TM[0];
        unsigned short* Vt = TM[0] + 8192;
#pragma unroll
        for (int j = 0; j < 4; ++j) {
            int ci = t + 256 * j;
            gload16(Ksrc + koff[j], &Kt[ci * 8]);
            gload16(Vsrc + voff[j], &Vt[ci * 8]);
        }
    }
    __syncthreads();

    int cur = 0;
    for (int it = 0; it < NIT; ++it) {
        if (it + 1 < NIT) {
            const int kb2 = kbeg + (it + 1) * 64;
            const unsigned short* Ksrc = Kb + (size_t)kb2 * C_DIM;
            const unsigned short* Vsrc = Vb + kb2;
            unsigned short* Kt2 = TM[cur ^ 1];
            unsigned short* Vt2 = TM[cur ^ 1] + 8192;
#pragma unroll
            for (int j = 0; j < 4; ++j) {
                int ci = t + 256 * j;
                gload16(Ksrc + koff[j], &Kt2[ci * 8]);
                gload16(Vsrc + voff[j], &Vt2[ci * 8]);
            }
        }

        unsigned short* Kt = TM[cur];
        unsigned short* Vt = TM[cur] + 8192;

        f32x4 S[3][4];
#pragma unroll
        for (int rt = 0; rt < 3; ++rt)
#pragma unroll
            for (int n = 0; n < 4; ++n) S[rt][n] = (f32x4){0.f, 0.f, 0.f, 0.f};
#pragma unroll
        for (int n = 0; n < 4; ++n)
#pragma unroll
            for (int s = 0; s < 4; ++s) {
                short8 kf = *(const short8*)
                    &Kt[(size_t)(n * 16 + l16) * 128 + (((4 * s + quad) ^ l16) * 8)];
                S[0][n] = mfma_bf16(qf[0][s], kf, S[0][n]);
                S[1][n] = mfma_bf16(qf[1][s], kf, S[1][n]);
                S[2][n] = mfma_bf16(qf[2][s], kf, S[2][n]);
            }

        short8 pa[3][2];
#pragma unroll
        for (int rt = 0; rt < 3; ++rt) {
#pragma unroll
            for (int n = 0; n < 4; ++n)
#pragma unroll
                for (int r = 0; r < 4; ++r) {
                    float e = __builtin_amdgcn_exp2f(S[rt][n][r]);
                    lsum[rt][r] += e;
                    int row = quad * 4 + r;
                    Plds[wave][row][(((n * 2 + (l16 >> 3)) ^ (row & 7)) << 3) | (l16 & 7)] =
                        f2bf(e);
                }
            pa[rt][0] = *(const short8*)&Plds[wave][l16][((quad       ^ (l16 & 7)) << 3)];
            pa[rt][1] = *(const short8*)&Plds[wave][l16][(((4 + quad) ^ (l16 & 7)) << 3)];
        }

        const int m = l16 & 7;
#pragma unroll
        for (int h = 0; h < 8; ++h) {
            short8 v0 = *(const short8*)&Vt[(size_t)(h * 16 + l16) * 64 + ((quad ^ m) * 8)];
            short8 v1 = *(const short8*)&Vt[(size_t)(h * 16 + l16) * 64 + (((quad + 4) ^ m) * 8)];
            O[0][h] = mfma_bf16(pa[0][0], v0, O[0][h]);
            O[0][h] = mfma_bf16(pa[0][1], v1, O[0][h]);
            O[1][h] = mfma_bf16(pa[1][0], v0, O[1][h]);
            O[1][h] = mfma_bf16(pa[1][1], v1, O[1][h]);
            O[2][h] = mfma_bf16(pa[2][0], v0, O[2][h]);
            O[2][h] = mfma_bf16(pa[2][1], v1, O[2][h]);
        }

        __syncthreads();
        cur ^= 1;
    }

#pragma unroll
    for (int off = 1; off < 16; off <<= 1)
#pragma unroll
        for (int rt = 0; rt < 3; ++rt)
#pragma unroll
            for (int r = 0; r < 4; ++r)
                lsum[rt][r] += __shfl_xor(lsum[rt][r], off, 64);

    // ---- write P/L partials (interleaved layout) ----
#pragma unroll
    for (int rt = 0; rt < 3; ++rt)
#pragma unroll
        for (int r = 0; r < 4; ++r) {
            int lrow = wave * 48 + rt * 16 + quad * 4 + r;
            size_t row = (size_t)fb * HW_DIM + qblk * 192 + lrow;
            if (l16 == 0) Lint[row * NSPLIT + ks] = lsum[rt][r];
#pragma unroll
            for (int h = 0; h < 8; ++h)
                Pint[row * (NSPLIT * C_DIM) + ks * C_DIM + h * 16 + l16] =
                    f2bf(O[rt][h][r]);
        }
}

// ---------------------------------------------------------------------------
// Launch C: combine + out-conv + residual (T14 load batching; best-proven).
// ---------------------------------------------------------------------------
template <int NPARTS>
__global__ __launch_bounds__(256)
void combine_out(const unsigned short* __restrict__ Pint,
                 const float* __restrict__ Lint,
                 const float* __restrict__ OW,
                 const float* __restrict__ OG,
                 const float* __restrict__ OB,
                 const float* __restrict__ RESID,
                 float* __restrict__ OUT)
{
    __shared__ __align__(16) unsigned short Xt[32 * 128];   // 8 KB
    __shared__ float invl[32];

    const int t    = threadIdx.x;
    const int b    = blockIdx.y;
    const int p0   = blockIdx.x * 32;
    const int wave = t >> 6;
    const int lane = t & 63;
    const int quad = lane >> 4;
    const int l16  = lane & 15;
    const float BNRS = 0.99999500003749972f;

    // ---- T14: issue ALL partial loads first ----
    uint4 pv[2][NPARTS];
#pragma unroll
    for (int i = 0; i < 2; ++i) {
        int idx = t + 256 * i;
        int p = idx >> 4, ch = idx & 15;
        size_t row = (size_t)b * HW_DIM + p0 + p;
        size_t base = row * (NPARTS * C_DIM) + ch * 8;
#pragma unroll
        for (int pr = 0; pr < NPARTS; ++pr)
            pv[i][pr] = *(const uint4*)&Pint[base + (size_t)pr * C_DIM];
    }

    // ---- W fragments (L2) while partials stream ----
    short8 af[2][4];
#pragma unroll
    for (int mi = 0; mi < 2; ++mi) {
        int o = (wave * 2 + mi) * 16 + l16;
#pragma unroll
        for (int s = 0; s < 4; ++s)
            af[mi][s] = wfrag(OW + o * C_DIM + s * 32 + quad * 8);
    }

    if (t < 32) {
        size_t row = (size_t)b * HW_DIM + p0 + t;
        float s = 0.f;
#pragma unroll
        for (int pr = 0; pr < NPARTS; ++pr)
            s += Lint[row * NPARTS + pr];
        invl[t] = 1.0f / s;
    }
    __syncthreads();

    // ---- accumulate + normalize -> Xt ----
#pragma unroll
    for (int i = 0; i < 2; ++i) {
        int idx = t + 256 * i;
        int p = idx >> 4, ch = idx & 15;
        float acc8[8] = {0.f, 0.f, 0.f, 0.f, 0.f, 0.f, 0.f, 0.f};
#pragma unroll
        for (int pr = 0; pr < NPARTS; ++pr) {
            const unsigned int* ap = (const unsigned int*)&pv[i][pr];
#pragma unroll
            for (int j = 0; j < 4; ++j) {
                acc8[2 * j]     += bf2f((unsigned short)(ap[j] & 0xFFFF));
                acc8[2 * j + 1] += bf2f((unsigned short)(ap[j] >> 16));
            }
        }
        float s = invl[p];
        unsigned int w[4];
#pragma unroll
        for (int j = 0; j < 4; ++j)
            w[j] = pack2(acc8[2 * j] * s, acc8[2 * j + 1] * s);
        *(uint4*)&Xt[p * 128 + ((ch ^ (p & 15)) * 8)] = *(uint4*)w;
    }
    __syncthreads();

    f32x4 acc[2][2];
#pragma unroll
    for (int mi = 0; mi < 2; ++mi)
#pragma unroll
        for (int nt = 0; nt < 2; ++nt) acc[mi][nt] = (f32x4){0.f, 0.f, 0.f, 0.f};
#pragma unroll
    for (int nt = 0; nt < 2; ++nt)
#pragma unroll
        for (int s = 0; s < 4; ++s) {
            short8 bf = *(const short8*)
                &Xt[(nt * 16 + l16) * 128 + (((4 * s + quad) ^ l16) * 8)];
            acc[0][nt] = mfma_bf16(af[0][s], bf, acc[0][nt]);
            acc[1][nt] = mfma_bf16(af[1][s], bf, acc[1][nt]);
        }

#pragma unroll
    for (int mi = 0; mi < 2; ++mi)
#pragma unroll
        for (int r = 0; r < 4; ++r) {
            int o = (wave * 2 + mi) * 16 + quad * 4 + r;
            float sc = OG[o] * BNRS, bb = OB[o];
#pragma unroll
            for (int nt = 0; nt < 2; ++nt) {
                float y = fmaf(acc[mi][nt][r], sc, bb);
                y = y > 0.f ? y : 0.1f * y;
                size_t g = ((size_t)b * C_DIM + o) * HW_DIM + p0 + nt * 16 + l16;
                OUT[g] = y + RESID[g];
            }
        }
}

// ---------------------------------------------------------------------------
extern "C" void kernel_launch(void* const* d_in, const int* in_sizes, int n_in,
                              void* d_out, int out_size, void* d_ws, size_t ws_size,
                              hipStream_t stream)
{
    // Workspace: [ Pint: nsplit*3145728 B ][ Qbf ][ Kbf ][ Vbf ][ Lint: nsplit*49152 B ]
    const size_t PPART = (size_t)2 * HW_DIM * C_DIM * 2;  // 3,145,728 B
    const size_t LPART = (size_t)2 * HW_DIM * 4;          // 49,152 B
    const int nsplit = (ws_size >= 11 * PPART + 8 * LPART) ? 8 : 4;

    char* ws = (char*)d_ws;
    unsigned short* Pint = (unsigned short*)ws;
    unsigned short* Qbf = (unsigned short*)(ws + (size_t)nsplit * PPART);
    unsigned short* Kbf = (unsigned short*)(ws + (size_t)nsplit * PPART + PPART);
    unsigned short* Vbf = (unsigned short*)(ws + (size_t)nsplit * PPART + 2 * PPART);
    float*          Lint = (float*)(ws + (size_t)nsplit * PPART + 3 * PPART);
    float* outp = (float*)d_out;

    // Launch A: QKV projections, key staged once. Grid (96,2,2)=384 blocks.
    {
        ProjArgs pa;
        pa.query = (const float*)d_in[0];
        pa.key   = (const float*)d_in[1];
        pa.q_w1 = (const float*)d_in[2];  pa.q_g1 = (const float*)d_in[3];
        pa.q_b1 = (const float*)d_in[4];
        pa.q_w2 = (const float*)d_in[5];  pa.q_g2 = (const float*)d_in[6];
        pa.q_b2 = (const float*)d_in[7];
        pa.k_w1 = (const float*)d_in[8];  pa.k_g1 = (const float*)d_in[9];
        pa.k_b1 = (const float*)d_in[10];
        pa.k_w2 = (const float*)d_in[11]; pa.k_g2 = (const float*)d_in[12];
        pa.k_b2 = (const float*)d_in[13];
        pa.v_w  = (const float*)d_in[14]; pa.v_g  = (const float*)d_in[15];
        pa.v_b  = (const float*)d_in[16];
        pa.Qbf = Qbf; pa.Kbf = Kbf; pa.Vbf = Vbf;
        pa.qscale = 0.08838834764831845f * 1.44269504088896340f;
        hipLaunchKernelGGL(qkv_proj, dim3(HW_DIM / 64, 2, 2), dim3(256),
                           0, stream, pa);
    }

    // Flash: dbuf pipeline, interleaved P/L writes. 512 blocks (2/CU), rt=3.
    if (nsplit == 8) {
        hipLaunchKernelGGL(HIP_KERNEL_NAME(flash_attn<8>),
                           dim3(2 * (HW_DIM / 192) * 8), dim3(256),
                           0, stream, Qbf, Kbf, Vbf, Pint, Lint);
    } else {
        hipLaunchKernelGGL(HIP_KERNEL_NAME(flash_attn<4>),
                           dim3(2 * (HW_DIM / 192) * 4), dim3(256),
                           0, stream, Qbf, Kbf, Vbf, Pint, Lint);
    }

    // Launch C: combine (batched streaming reads) + out-conv + residual.
    {
        const float* o_w = (const float*)d_in[17];
        const float* o_g = (const float*)d_in[18];
        const float* o_b = (const float*)d_in[19];
        if (nsplit == 8) {
            hipLaunchKernelGGL(HIP_KERNEL_NAME(combine_out<8>),
                               dim3(HW_DIM / 32, 2), dim3(256), 0, stream,
                               Pint, Lint, o_w, o_g, o_b,
                               (const float*)d_in[0], outp);
        } else {
            hipLaunchKernelGGL(HIP_KERNEL_NAME(combine_out<4>),
                               dim3(HW_DIM / 32, 2), dim3(256), 0, stream,
                               Pint, Lint, o_w, o_g, o_b,
                               (const float*)d_in[0], outp);
        }
    }
}